// Round 1
// baseline (698.202 us; speedup 1.0000x reference)
//
#include <hip/hip_runtime.h>
#include <hip/hip_bf16.h>

#define NB 8
#define NN 2048
#define ND 256
#define SCALE 0.1767766952966369f   // 1/sqrt(32)

typedef __attribute__((ext_vector_type(8))) short short8;
typedef __attribute__((ext_vector_type(4))) float f32x4;
typedef unsigned short ushort_t;

static __device__ __forceinline__ ushort_t f2b(float f) {
    union { float f; unsigned int u; } v; v.f = f;
    unsigned int r = (v.u + 0x7FFFu + ((v.u >> 16) & 1u)) >> 16;  // RNE
    return (ushort_t)r;
}

static __device__ __forceinline__ float sigmoidf_(float x) {
    return 1.0f / (1.0f + __expf(-x));
}

// ---------------- K1: deg[b,n] = sum_m rel_pos[b,n,m] ----------------
__global__ __launch_bounds__(256) void deg_kernel(const float* __restrict__ rel,
                                                  float* __restrict__ deg) {
    const int row = blockIdx.x;                    // 0 .. NB*NN-1
    const float4* r4 = reinterpret_cast<const float4*>(rel + (size_t)row * NN);
    const int t = threadIdx.x;
    float4 a = r4[t * 2];
    float4 b = r4[t * 2 + 1];
    float s = a.x + a.y + a.z + a.w + b.x + b.y + b.z + b.w;
    for (int off = 1; off < 64; off <<= 1) s += __shfl_xor(s, off, 64);
    __shared__ float ws[4];
    if ((t & 63) == 0) ws[t >> 6] = s;
    __syncthreads();
    if (t == 0) deg[row] = ws[0] + ws[1] + ws[2] + ws[3];
}

// ---------------- K1b: xg = bf16(x * sigmoid(deg*Wd + bd)) ----------------
__global__ __launch_bounds__(256) void gate_kernel(const float* __restrict__ x,
                                                   const float* __restrict__ deg,
                                                   const float* __restrict__ Wd,
                                                   const float* __restrict__ bd,
                                                   ushort_t* __restrict__ xg) {
    const int idx = (blockIdx.x * 256 + threadIdx.x) * 4;
    const int n = idx >> 8;
    const int d = idx & 255;
    const float dg = deg[n];
    float4 xv = *reinterpret_cast<const float4*>(x + idx);
    float4 wv = *reinterpret_cast<const float4*>(Wd + d);
    float4 bv = *reinterpret_cast<const float4*>(bd + d);
    ushort4 o;
    o.x = f2b(xv.x * sigmoidf_(dg * wv.x + bv.x));
    o.y = f2b(xv.y * sigmoidf_(dg * wv.y + bv.y));
    o.z = f2b(xv.z * sigmoidf_(dg * wv.z + bv.z));
    o.w = f2b(xv.w * sigmoidf_(dg * wv.w + bv.w));
    *reinterpret_cast<ushort4*>(xg + idx) = o;
}

// ---------------- K1c: W_qkv f32 -> bf16 ----------------
__global__ __launch_bounds__(256) void wconv_kernel(const float* __restrict__ W,
                                                    ushort_t* __restrict__ Wb) {
    const int idx = (blockIdx.x * 256 + threadIdx.x) * 4;
    float4 wv = *reinterpret_cast<const float4*>(W + idx);
    ushort4 o;
    o.x = f2b(wv.x); o.y = f2b(wv.y); o.z = f2b(wv.z); o.w = f2b(wv.w);
    *reinterpret_cast<ushort4*>(Wb + idx) = o;
}

// ---------------- K2: qkv = Xg @ W^T + b; split/transform outputs ----------------
// grid (NB*NN/64, 12), block 256 (4 waves, each 16 rows x 64 cols)
__global__ __launch_bounds__(256) void qkv_kernel(const ushort_t* __restrict__ xg,
                                                  const ushort_t* __restrict__ Wb,
                                                  const float* __restrict__ bqkv,
                                                  ushort_t* __restrict__ qk,
                                                  ushort_t* __restrict__ vT,
                                                  float* __restrict__ res) {
    const int t = threadIdx.x;
    const int w = t >> 6;
    const int l = t & 63;
    const int lr = l & 15;
    const int lg = l >> 4;
    const int n0 = blockIdx.x * 64 + w * 16;
    const int c0 = blockIdx.y * 64;

    f32x4 acc[4];
#pragma unroll
    for (int i = 0; i < 4; ++i) acc[i] = (f32x4){0.f, 0.f, 0.f, 0.f};

#pragma unroll
    for (int kb = 0; kb < 8; ++kb) {
        short8 a = *reinterpret_cast<const short8*>(xg + (size_t)(n0 + lr) * ND + kb * 32 + lg * 8);
#pragma unroll
        for (int ct = 0; ct < 4; ++ct) {
            short8 bb = *reinterpret_cast<const short8*>(Wb + (size_t)(c0 + ct * 16 + lr) * ND + kb * 32 + lg * 8);
            acc[ct] = __builtin_amdgcn_mfma_f32_16x16x32_bf16(a, bb, acc[ct], 0, 0, 0);
        }
    }

#pragma unroll
    for (int ct = 0; ct < 4; ++ct) {
        const int e = c0 + ct * 16 + lr;
        const float bias = bqkv[e];
#pragma unroll
        for (int r = 0; r < 4; ++r) {
            const int n = n0 + lg * 4 + r;
            float v = acc[ct][r] + bias;
            if (e < 256) {
                qk[(size_t)n * ND + e] = f2b(sigmoidf_(v));
            } else if (e < 512) {
                vT[((size_t)(n >> 11) * ND + (e - 256)) * NN + (n & 2047)] = f2b(v);
            } else {
                res[(size_t)n * ND + (e - 512)] = v;
            }
        }
    }
}

// ---------------- K3: streaming normalized attention ----------------
// grid (NN/64, NB), block 256: 4 waves, each owns 16 query rows, loops all m.
__global__ __launch_bounds__(256) void attn_kernel(const ushort_t* __restrict__ qk,
                                                   const ushort_t* __restrict__ vT,
                                                   const float* __restrict__ rel,
                                                   const float* __restrict__ res,
                                                   float* __restrict__ out) {
    __shared__ __align__(16) ushort_t slds[4][16][40];   // per-wave S tile, 80B row stride
    const int t = threadIdx.x;
    const int w = t >> 6;
    const int l = t & 63;
    const int lr = l & 15;
    const int lg = l >> 4;
    const int b = blockIdx.y;
    const int q0 = blockIdx.x * 64 + w * 16;

    const ushort_t* qkb = qk + (size_t)b * NN * ND;
    const ushort_t* vTb = vT + (size_t)b * ND * NN;
    const float* relb = rel + (size_t)b * NN * NN;

    // hoist Q fragments (A-layout: row = lane&15, k = (lane>>4)*8 + j)
    short8 aq[8];
#pragma unroll
    for (int kb = 0; kb < 8; ++kb)
        aq[kb] = *reinterpret_cast<const short8*>(qkb + (size_t)(q0 + lr) * ND + kb * 32 + lg * 8);

    f32x4 acc[16];
#pragma unroll
    for (int i = 0; i < 16; ++i) acc[i] = (f32x4){0.f, 0.f, 0.f, 0.f};
    float dsum[4] = {0.f, 0.f, 0.f, 0.f};

    for (int mt = 0; mt < 64; ++mt) {
        const int m0 = mt * 32;
        // S[16q][32m] = Q . K^T over K=256 (two 16x16 D-tiles)
        f32x4 s0 = (f32x4){0.f, 0.f, 0.f, 0.f};
        f32x4 s1 = (f32x4){0.f, 0.f, 0.f, 0.f};
#pragma unroll
        for (int kb = 0; kb < 8; ++kb) {
            short8 b0 = *reinterpret_cast<const short8*>(qkb + (size_t)(m0 + lr) * ND + kb * 32 + lg * 8);
            short8 b1 = *reinterpret_cast<const short8*>(qkb + (size_t)(m0 + 16 + lr) * ND + kb * 32 + lg * 8);
            s0 = __builtin_amdgcn_mfma_f32_16x16x32_bf16(aq[kb], b0, s0, 0, 0, 0);
            s1 = __builtin_amdgcn_mfma_f32_16x16x32_bf16(aq[kb], b1, s1, 0, 0, 0);
        }
        // scale * rel_pos, denom accumulate, stage S (bf16) to LDS for transpose
#pragma unroll
        for (int r = 0; r < 4; ++r) {
            const int qrow = q0 + lg * 4 + r;
            float rp0 = relb[(size_t)qrow * NN + m0 + lr];
            float rp1 = relb[(size_t)qrow * NN + m0 + 16 + lr];
            float v0 = s0[r] * SCALE * rp0;
            float v1 = s1[r] * SCALE * rp1;
            dsum[r] += v0 + v1;
            slds[w][lg * 4 + r][lr] = f2b(v0);
            slds[w][lg * 4 + r][16 + lr] = f2b(v1);
        }
        asm volatile("" ::: "memory");   // keep ds_write before ds_read (same wave, in-order DS pipe)
        short8 pa = *reinterpret_cast<const short8*>(&slds[w][lr][lg * 8]);
        asm volatile("" ::: "memory");
        // numer[16q][256d] += S(16x32m) . V(32m x 256d) from vT (B-frag contiguous)
#pragma unroll
        for (int dt = 0; dt < 16; ++dt) {
            short8 bv = *reinterpret_cast<const short8*>(vTb + (size_t)(dt * 16 + lr) * NN + m0 + lg * 8);
            acc[dt] = __builtin_amdgcn_mfma_f32_16x16x32_bf16(pa, bv, acc[dt], 0, 0, 0);
        }
    }

    // denom: reduce over the 16 lanes of each group (cols of S)
#pragma unroll
    for (int r = 0; r < 4; ++r) {
        float v = dsum[r];
        v += __shfl_xor(v, 1, 64);
        v += __shfl_xor(v, 2, 64);
        v += __shfl_xor(v, 4, 64);
        v += __shfl_xor(v, 8, 64);
        dsum[r] = v;
    }
    float inv[4];
#pragma unroll
    for (int r = 0; r < 4; ++r) inv[r] = 1.0f / (dsum[r] + 1e-6f);

#pragma unroll
    for (int dt = 0; dt < 16; ++dt) {
#pragma unroll
        for (int r = 0; r < 4; ++r) {
            const size_t o = ((size_t)b * NN + q0 + lg * 4 + r) * ND + dt * 16 + lr;
            float v = acc[dt][r] * inv[r] + res[o];
            out[o] = fmaxf(v, 0.f);
        }
    }
}

extern "C" void kernel_launch(void* const* d_in, const int* in_sizes, int n_in,
                              void* d_out, int out_size, void* d_ws, size_t ws_size,
                              hipStream_t stream) {
    const float* x    = (const float*)d_in[0];
    const float* rel  = (const float*)d_in[1];
    const float* Wqkv = (const float*)d_in[2];
    const float* bqkv = (const float*)d_in[3];
    const float* Wd   = (const float*)d_in[4];
    const float* bd   = (const float*)d_in[5];
    float* out = (float*)d_out;

    char* ws = (char*)d_ws;
    float*    deg = (float*)(ws + 0);                  //  64 KB
    ushort_t* Wb  = (ushort_t*)(ws + 0x10000);         // 384 KB
    ushort_t* xg  = (ushort_t*)(ws + 0x80000);         //   8 MB
    ushort_t* qkb = (ushort_t*)(ws + 0x880000);        //   8 MB
    ushort_t* vT  = (ushort_t*)(ws + 0x1080000);       //   8 MB
    float*    res = (float*)(ws + 0x1880000);          //  16 MB

    deg_kernel<<<NB * NN, 256, 0, stream>>>(rel, deg);
    gate_kernel<<<(NB * NN * ND) / 1024, 256, 0, stream>>>(x, deg, Wd, bd, xg);
    wconv_kernel<<<(3 * ND * ND) / 1024, 256, 0, stream>>>(Wqkv, Wb);
    qkv_kernel<<<dim3(NB * NN / 64, 12), 256, 0, stream>>>(xg, Wb, bqkv, qkb, vT, res);
    attn_kernel<<<dim3(NN / 64, NB), 256, 0, stream>>>(qkb, vT, rel, res, out);
}

// Round 3
// 502.656 us; speedup vs baseline: 1.3890x; 1.3890x over previous
//
#include <hip/hip_runtime.h>
#include <hip/hip_bf16.h>

#define NB 8
#define NN 2048
#define ND 256
#define SCALE 0.1767766952966369f   // 1/sqrt(32)

typedef __attribute__((ext_vector_type(8))) short short8;
typedef __attribute__((ext_vector_type(4))) float f32x4;
typedef unsigned short ushort_t;

static __device__ __forceinline__ ushort_t f2b(float f) {
    union { float f; unsigned int u; } v; v.f = f;
    unsigned int r = (v.u + 0x7FFFu + ((v.u >> 16) & 1u)) >> 16;  // RNE
    return (ushort_t)r;
}

static __device__ __forceinline__ float sigmoidf_(float x) {
    return 1.0f / (1.0f + __expf(-x));
}

// ---------------- K1: deg = rowsum(rel); xg = bf16(x * sigmoid(deg*Wd + bd)) ----------------
// one block per (b,n) row: 256 threads read the 2048-float rel row + gate 256 dims of x
__global__ __launch_bounds__(256) void deggate_kernel(const float* __restrict__ rel,
                                                      const float* __restrict__ x,
                                                      const float* __restrict__ Wd,
                                                      const float* __restrict__ bd,
                                                      ushort_t* __restrict__ xg) {
    const int row = blockIdx.x;                    // 0 .. NB*NN-1
    const int t = threadIdx.x;
    const float4* r4 = reinterpret_cast<const float4*>(rel + (size_t)row * NN);
    float4 a = r4[t * 2];
    float4 b = r4[t * 2 + 1];
    float s = a.x + a.y + a.z + a.w + b.x + b.y + b.z + b.w;
    for (int off = 1; off < 64; off <<= 1) s += __shfl_xor(s, off, 64);
    __shared__ float ws[4];
    if ((t & 63) == 0) ws[t >> 6] = s;
    __syncthreads();
    const float dg = ws[0] + ws[1] + ws[2] + ws[3];
    const float xv = x[(size_t)row * ND + t];
    xg[(size_t)row * ND + t] = f2b(xv * sigmoidf_(dg * Wd[t] + bd[t]));
}

// ---------------- K1c: W_qkv f32 -> bf16 ----------------
__global__ __launch_bounds__(256) void wconv_kernel(const float* __restrict__ W,
                                                    ushort_t* __restrict__ Wb) {
    const int idx = (blockIdx.x * 256 + threadIdx.x) * 4;
    float4 wv = *reinterpret_cast<const float4*>(W + idx);
    ushort4 o;
    o.x = f2b(wv.x); o.y = f2b(wv.y); o.z = f2b(wv.z); o.w = f2b(wv.w);
    *reinterpret_cast<ushort4*>(Wb + idx) = o;
}

// ---------------- K2: qkv = Xg @ W^T + b; split/transform outputs ----------------
// grid (NB*NN/64, 12), block 256 (4 waves, each 16 rows x 64 cols)
__global__ __launch_bounds__(256) void qkv_kernel(const ushort_t* __restrict__ xg,
                                                  const ushort_t* __restrict__ Wb,
                                                  const float* __restrict__ bqkv,
                                                  ushort_t* __restrict__ qk,
                                                  ushort_t* __restrict__ vT,
                                                  float* __restrict__ res) {
    __shared__ __align__(16) ushort_t T[64][72];       // e_loc x n_loc transpose tile (9 KB)
    const int t = threadIdx.x;
    const int w = t >> 6;
    const int l = t & 63;
    const int lr = l & 15;
    const int lg = l >> 4;
    const int n0 = blockIdx.x * 64 + w * 16;
    const int c0 = blockIdx.y * 64;

    f32x4 acc[4];
#pragma unroll
    for (int i = 0; i < 4; ++i) acc[i] = (f32x4){0.f, 0.f, 0.f, 0.f};

#pragma unroll
    for (int kb = 0; kb < 8; ++kb) {
        short8 a = *reinterpret_cast<const short8*>(xg + (size_t)(n0 + lr) * ND + kb * 32 + lg * 8);
#pragma unroll
        for (int ct = 0; ct < 4; ++ct) {
            short8 bb = *reinterpret_cast<const short8*>(Wb + (size_t)(c0 + ct * 16 + lr) * ND + kb * 32 + lg * 8);
            acc[ct] = __builtin_amdgcn_mfma_f32_16x16x32_bf16(a, bb, acc[ct], 0, 0, 0);
        }
    }

    if (blockIdx.y < 4) {
        // qk = sigmoid(...) -> bf16, direct store
#pragma unroll
        for (int ct = 0; ct < 4; ++ct) {
            const int e = c0 + ct * 16 + lr;
            const float bias = bqkv[e];
#pragma unroll
            for (int r = 0; r < 4; ++r) {
                const int n = n0 + lg * 4 + r;
                qk[(size_t)n * ND + e] = f2b(sigmoidf_(acc[ct][r] + bias));
            }
        }
    } else if (blockIdx.y < 8) {
        // value -> vT[b][d][n], transposed through LDS for coalesced writes
#pragma unroll
        for (int ct = 0; ct < 4; ++ct) {
            const int e = c0 + ct * 16 + lr;
            const float bias = bqkv[e];
#pragma unroll
            for (int r = 0; r < 4; ++r)
                T[ct * 16 + lr][w * 16 + lg * 4 + r] = f2b(acc[ct][r] + bias);
        }
        __syncthreads();
        const int e_loc = t >> 2;
        const int nl = (t & 3) * 16;
        const int d = c0 - 256 + e_loc;
        const int ng = blockIdx.x * 64;
        const int b = ng >> 11;
        size_t base = ((size_t)b * ND + d) * NN + (ng & 2047) + nl;
        *reinterpret_cast<short8*>(vT + base)     = *reinterpret_cast<const short8*>(&T[e_loc][nl]);
        *reinterpret_cast<short8*>(vT + base + 8) = *reinterpret_cast<const short8*>(&T[e_loc][nl + 8]);
    } else {
        // res, f32 direct store
#pragma unroll
        for (int ct = 0; ct < 4; ++ct) {
            const int e = c0 + ct * 16 + lr;
            const float bias = bqkv[e];
#pragma unroll
            for (int r = 0; r < 4; ++r) {
                const int n = n0 + lg * 4 + r;
                res[(size_t)n * ND + (e - 512)] = acc[ct][r] + bias;
            }
        }
    }
}

// ---------------- K3: streaming normalized attention ----------------
// grid (NN/16, NB), block 256: 4 waves share 16 q rows.
// Phase A: wave w computes S for its 32-wide m-slice of a 128-wide m-tile -> LDS.
// Phase B: wave w computes PV for its 64-wide d-quadrant over the full 128 m.
__global__ __launch_bounds__(256, 4) void attn_kernel(const ushort_t* __restrict__ qk,
                                                      const ushort_t* __restrict__ vT,
                                                      const float* __restrict__ rel,
                                                      const float* __restrict__ res,
                                                      float* __restrict__ out) {
    __shared__ __align__(16) ushort_t slds[2][16][144];   // S tile, 288B row stride (16B-mult)
    __shared__ float dsums[4][16];
    const int t = threadIdx.x;
    const int w = t >> 6;
    const int l = t & 63;
    const int lr = l & 15;
    const int lg = l >> 4;
    const int b = blockIdx.y;
    const int q0 = blockIdx.x * 16;

    const ushort_t* qkb = qk + (size_t)b * NN * ND;
    const ushort_t* vTb = vT + (size_t)b * ND * NN;
    const float* relb = rel + (size_t)b * NN * NN;

    // hoist Q fragments (A-layout: row = lane&15, k = (lane>>4)*8 + j)
    short8 aq[8];
#pragma unroll
    for (int kb = 0; kb < 8; ++kb)
        aq[kb] = *reinterpret_cast<const short8*>(qkb + (size_t)(q0 + lr) * ND + kb * 32 + lg * 8);

    f32x4 acc[4];
#pragma unroll
    for (int i = 0; i < 4; ++i) acc[i] = (f32x4){0.f, 0.f, 0.f, 0.f};
    float dsum[4] = {0.f, 0.f, 0.f, 0.f};

    for (int mt = 0; mt < 16; ++mt) {
        const int m0 = mt * 128;
        const int mw = m0 + w * 32;
        const int buf = mt & 1;

        // issue rel loads early (independent of the MFMA chain)
        float rp0[4], rp1[4];
#pragma unroll
        for (int r = 0; r < 4; ++r) {
            const int qrow = q0 + lg * 4 + r;
            rp0[r] = relb[(size_t)qrow * NN + mw + lr];
            rp1[r] = relb[(size_t)qrow * NN + mw + 16 + lr];
        }

        // S[16q][32m] = Q . K^T over K=256
        f32x4 s0 = (f32x4){0.f, 0.f, 0.f, 0.f};
        f32x4 s1 = (f32x4){0.f, 0.f, 0.f, 0.f};
#pragma unroll
        for (int kb = 0; kb < 8; ++kb) {
            short8 b0 = *reinterpret_cast<const short8*>(qkb + (size_t)(mw + lr) * ND + kb * 32 + lg * 8);
            short8 b1 = *reinterpret_cast<const short8*>(qkb + (size_t)(mw + 16 + lr) * ND + kb * 32 + lg * 8);
            s0 = __builtin_amdgcn_mfma_f32_16x16x32_bf16(aq[kb], b0, s0, 0, 0, 0);
            s1 = __builtin_amdgcn_mfma_f32_16x16x32_bf16(aq[kb], b1, s1, 0, 0, 0);
        }

        // scale * rel_pos, denom accumulate, stage S (bf16) to LDS
#pragma unroll
        for (int r = 0; r < 4; ++r) {
            float v0 = s0[r] * SCALE * rp0[r];
            float v1 = s1[r] * SCALE * rp1[r];
            dsum[r] += v0 + v1;
            slds[buf][lg * 4 + r][w * 32 + lr] = f2b(v0);
            slds[buf][lg * 4 + r][w * 32 + 16 + lr] = f2b(v1);
        }
        __syncthreads();

        // PV: numer[16q][64d-quadrant] += S(16x128) . V(128 x d)
        short8 pa[4];
#pragma unroll
        for (int kt = 0; kt < 4; ++kt)
            pa[kt] = *reinterpret_cast<const short8*>(&slds[buf][lr][kt * 32 + lg * 8]);
#pragma unroll
        for (int dt = 0; dt < 4; ++dt) {
#pragma unroll
            for (int kt = 0; kt < 4; ++kt) {
                short8 bv = *reinterpret_cast<const short8*>(
                    vTb + (size_t)(w * 64 + dt * 16 + lr) * NN + m0 + kt * 32 + lg * 8);
                acc[dt] = __builtin_amdgcn_mfma_f32_16x16x32_bf16(pa[kt], bv, acc[dt], 0, 0, 0);
            }
        }
    }

    // denom: reduce over the 16 lanes of each group, then across the 4 waves
#pragma unroll
    for (int r = 0; r < 4; ++r) {
        float v = dsum[r];
        v += __shfl_xor(v, 1, 64);
        v += __shfl_xor(v, 2, 64);
        v += __shfl_xor(v, 4, 64);
        v += __shfl_xor(v, 8, 64);
        dsum[r] = v;
    }
    __syncthreads();
    if (lr == 0) {
#pragma unroll
        for (int r = 0; r < 4; ++r) dsums[w][lg * 4 + r] = dsum[r];
    }
    __syncthreads();
    float inv[4];
#pragma unroll
    for (int r = 0; r < 4; ++r) {
        const int q = lg * 4 + r;
        float tot = dsums[0][q] + dsums[1][q] + dsums[2][q] + dsums[3][q];
        inv[r] = 1.0f / (tot + 1e-6f);
    }

#pragma unroll
    for (int dt = 0; dt < 4; ++dt) {
#pragma unroll
        for (int r = 0; r < 4; ++r) {
            const size_t o = ((size_t)b * NN + q0 + lg * 4 + r) * ND + w * 64 + dt * 16 + lr;
            float v = acc[dt][r] * inv[r] + res[o];
            out[o] = fmaxf(v, 0.f);
        }
    }
}

extern "C" void kernel_launch(void* const* d_in, const int* in_sizes, int n_in,
                              void* d_out, int out_size, void* d_ws, size_t ws_size,
                              hipStream_t stream) {
    const float* x    = (const float*)d_in[0];
    const float* rel  = (const float*)d_in[1];
    const float* Wqkv = (const float*)d_in[2];
    const float* bqkv = (const float*)d_in[3];
    const float* Wd   = (const float*)d_in[4];
    const float* bd   = (const float*)d_in[5];
    float* out = (float*)d_out;

    char* ws = (char*)d_ws;
    ushort_t* Wb  = (ushort_t*)(ws + 0);               // 384 KB
    ushort_t* xg  = (ushort_t*)(ws + 0x80000);         //   8 MB
    ushort_t* qkb = (ushort_t*)(ws + 0x880000);        //   8 MB
    ushort_t* vT  = (ushort_t*)(ws + 0x1080000);       //   8 MB
    float*    res = (float*)(ws + 0x1880000);          //  16 MB

    deggate_kernel<<<NB * NN, 256, 0, stream>>>(rel, x, Wd, bd, xg);
    wconv_kernel<<<(3 * ND * ND) / 1024, 256, 0, stream>>>(Wqkv, Wb);
    qkv_kernel<<<dim3(NB * NN / 64, 12), 256, 0, stream>>>(xg, Wb, bqkv, qkb, vT, res);
    attn_kernel<<<dim3(NN / 16, NB), 256, 0, stream>>>(qkb, vT, rel, res, out);
}